// Round 10
// baseline (207.279 us; speedup 1.0000x reference)
//
#include <hip/hip_runtime.h>
#include <hip/hip_bf16.h>

// MambaStateSpaceLayer: B=2, S=1024, D_MODEL=1024, D_STATE=16, D_INNER=2048
// Round 10 (= r9 resubmit after infra failure): r8 frozen + T1 XCD-aware block
// swizzle on both GEMMs (bijective, grids % 8 == 0) + 8-wide cast kernel.

#define LOG2E 1.4426950408889634f

typedef float floatx4 __attribute__((ext_vector_type(4)));
typedef short short8 __attribute__((ext_vector_type(8)));

__device__ __forceinline__ float fexp2(float x) { return __builtin_amdgcn_exp2f(x); }
__device__ __forceinline__ unsigned short f2bf(float f) {
    unsigned int u = __float_as_uint(f);
    u = (u + 0x7fffu + ((u >> 16) & 1u)) >> 16;   // round-to-nearest-even
    return (unsigned short)u;
}
__device__ __forceinline__ float bf2f(unsigned short h) {
    return __uint_as_float(((unsigned int)h) << 16);
}

// async 16B global -> LDS. lp MUST be wave-uniform (HW adds lane*16).
#define GLDS16(gp, lp) __builtin_amdgcn_global_load_lds(                      \
    (const __attribute__((address_space(1))) void*)(gp),                      \
    (__attribute__((address_space(3))) void*)(lp), 16, 0, 0)

// ------- cast x, W_gate, W_in, W_out to bf16 + init out=bias (8 elems/thread)
__global__ __launch_bounds__(256) void cast_and_init(
    const float* __restrict__ x, const float* __restrict__ wg,
    const float* __restrict__ wi, const float* __restrict__ wo,
    unsigned short* __restrict__ ox, unsigned short* __restrict__ owg,
    unsigned short* __restrict__ owi, unsigned short* __restrict__ owo,
    const float* __restrict__ b_out, float* __restrict__ out)
{
    const int bid = blockIdx.x;
    if (bid < 5120) {
        const size_t e = ((size_t)bid * 256 + threadIdx.x) * 8;
        const float* src; unsigned short* dst; size_t off;
        if (e < 2097152)      { src = x;  dst = ox;  off = e; }
        else if (e < 4194304) { src = wg; dst = owg; off = e - 2097152; }
        else if (e < 8388608) { src = wi; dst = owi; off = e - 4194304; }
        else                  { src = wo; dst = owo; off = e - 8388608; }
        float4 v0 = *(const float4*)(src + off);
        float4 v1 = *(const float4*)(src + off + 4);
        short8 o;
        o[0] = (short)f2bf(v0.x); o[1] = (short)f2bf(v0.y);
        o[2] = (short)f2bf(v0.z); o[3] = (short)f2bf(v0.w);
        o[4] = (short)f2bf(v1.x); o[5] = (short)f2bf(v1.y);
        o[6] = (short)f2bf(v1.z); o[7] = (short)f2bf(v1.w);
        *(short8*)(dst + off) = o;
    } else {
        const size_t e = ((size_t)(bid - 5120) * 256 + threadIdx.x) * 8;
        const int col = (int)(e & 1023);
        *(float4*)(out + e)     = *(const float4*)(b_out + col);
        *(float4*)(out + e + 4) = *(const float4*)(b_out + col + 4);
    }
}

// ---------------- MFMA GEMM (r3 structure, r7 epilogue, T1 swizzle) ----------
// C = A[M,ldk] @ W[N,ldk]^T (+ bias).  BK=64 bf16 (128B rows, 8x16B slots).
// Staging: global_load_lds dwordx4, linear LDS dest; source slot pre-swizzled
// (l&7)^(l>>3); ds_read uses slot ^ (row&7)  [both-sides-or-neither].
// Block = 4 waves (2x2). Wave tile = (MI*16) x 64. BM = MI*32, BN = 128.
// T1: blocks dispatch round-robin to 8 XCDs by linear id; remap so each XCD's
// blocks form a y-major contiguous span (shared B/W panels stay in its L2).
// MODE 3 (MI=4, grid 48x16): fused input GEMM. vbx<16 -> gate=sigmoid; else
//   proj: n<2048 -> xproj, n>=2048 -> relu -> delta. bf16 out via LDS repack.
// MODE 2 (MI=2, grid 8x32x2): K-split over z; atomicAdd f32 into outp.
template <int MODE, int MI>
__global__ __launch_bounds__(256, 3) void gemm_mfma(
    const unsigned short* __restrict__ A,
    const unsigned short* __restrict__ W0,
    const unsigned short* __restrict__ W1,
    const float* __restrict__ bias0, const float* __restrict__ bias1,
    unsigned short* __restrict__ gate,
    unsigned short* __restrict__ xproj, unsigned short* __restrict__ delta,
    float* __restrict__ outp, int ldk, int Ksub)
{
    constexpr int BM = MI * 32;
    constexpr int ROWA = BM / 32;          // A 1KB staging blocks per wave
    constexpr int NSH = (MODE == 3) ? 16384 : (BM * 64 + 8192);
    __shared__ short smem[NSH];            // staging; MODE 3 reuses as repack buf
    short* Asd = smem;                     // BM*64 shorts
    short* Bsd = smem + BM * 64;           // 128*64 shorts

    const int tid = threadIdx.x;
    const int l = tid & 63, w = tid >> 6;

    // ----- T1 bijective XCD swizzle + virtual tile coords -----
    int vbx, vby, vbz = 0;
    if (MODE == 3) {
        const int lid = blockIdx.x + 48 * blockIdx.y;      // 0..767
        const int v = (lid & 7) * 96 + (lid >> 3);         // per-XCD chunk
        vby = v & 15; vbx = v >> 4;                        // y-major
    } else {
        const int lid = blockIdx.x + 8 * (blockIdx.y + 32 * blockIdx.z); // 0..511
        const int v = (lid & 7) * 64 + (lid >> 3);
        vby = v & 31; const int rest = v >> 5;
        vbx = rest & 7; vbz = rest >> 3;
    }
    const int mbase = vby * BM;
    const int kbeg = (MODE == 2) ? vbz * Ksub : 0;
    const int kend = kbeg + Ksub;

    const unsigned short* Wp; const float* bias = nullptr; int nbase; bool isGate = false;
    if (MODE == 3) {
        if (vbx < 16) { Wp = W0; bias = bias0; nbase = vbx * 128; isGate = true; }
        else          { Wp = W1; bias = bias1; nbase = (vbx - 16) * 128; }
    } else { Wp = W0; nbase = vbx * 128; }

    // per-lane staging source offsets (elements, k0 added per iter)
    const int rl = l >> 3;                 // row within 8-row block
    const int cs = (l & 7) ^ rl;           // inverse-swizzled source slot
    size_t aoff[ROWA], boff[4];
    #pragma unroll
    for (int j = 0; j < ROWA; ++j)
        aoff[j] = (size_t)(mbase + (w * ROWA + j) * 8 + rl) * ldk + cs * 8;
    #pragma unroll
    for (int j = 0; j < 4; ++j)
        boff[j] = (size_t)(nbase + (w * 4 + j) * 8 + rl) * ldk + cs * 8;

    const int wm = (w >> 1) * (MI * 16), wn = (w & 1) * 64;
    floatx4 acc[MI][4] = {};

    for (int k0 = kbeg; k0 < kend; k0 += 64) {
        __syncthreads();                   // prior tile's ds_reads complete
        #pragma unroll
        for (int j = 0; j < ROWA; ++j)
            GLDS16(A + aoff[j] + k0, &Asd[(w * ROWA + j) * 512]);
        #pragma unroll
        for (int j = 0; j < 4; ++j)
            GLDS16(Wp + boff[j] + k0, &Bsd[(w * 4 + j) * 512]);
        __syncthreads();                   // vmcnt(0) drained by compiler

        #pragma unroll
        for (int kk = 0; kk < 2; ++kk) {
            short8 af[MI], bfr[4];
            #pragma unroll
            for (int i = 0; i < MI; ++i) {
                const int row = wm + i * 16 + (l & 15);
                af[i] = *(const short8*)&Asd[row * 64 + (((kk * 4 + (l >> 4)) ^ (row & 7)) << 3)];
            }
            #pragma unroll
            for (int j = 0; j < 4; ++j) {
                const int row = wn + j * 16 + (l & 15);
                bfr[j] = *(const short8*)&Bsd[row * 64 + (((kk * 4 + (l >> 4)) ^ (row & 7)) << 3)];
            }
            #pragma unroll
            for (int i = 0; i < MI; ++i)
                #pragma unroll
                for (int j = 0; j < 4; ++j)
                    acc[i][j] = __builtin_amdgcn_mfma_f32_16x16x32_bf16(af[i], bfr[j], acc[i][j], 0, 0, 0);
        }
    }

    // epilogue: D col = lane&15, row = (lane>>4)*4 + reg  [m89-verified]
    const int mt = wm + (l >> 4) * 4;      // tile-local row base
    const int nt = wn + (l & 15);          // tile-local col base
    if (MODE == 3) {
        // 1) bf16 tile -> LDS [128][128]
        __syncthreads();                   // staging reads done; reuse smem
        unsigned short* lout = (unsigned short*)smem;
        #pragma unroll
        for (int j = 0; j < 4; ++j) {
            const float bb = bias[nbase + nt + j * 16];
            #pragma unroll
            for (int i = 0; i < MI; ++i) {
                #pragma unroll
                for (int r = 0; r < 4; ++r) {
                    float v = acc[i][j][r] + bb;
                    if (isGate) v = 1.0f / (1.0f + fexp2(-v * LOG2E));
                    else if (nbase >= 2048) v = fmaxf(v, 0.0f);
                    lout[(mt + i * 16 + r) * 128 + nt + j * 16] = f2bf(v);
                }
            }
        }
        __syncthreads();
        // 2) coalesced linear copy LDS -> global (full 64B+ lines)
        unsigned short* dst = isGate ? gate : (nbase < 2048 ? xproj : delta);
        const int ncb = nbase & 2047;      // col base within 2048-wide buffer
        #pragma unroll
        for (int it = 0; it < 8; ++it) {
            const int so = it * 2048 + tid * 8;       // short offset in tile
            const int mrow = so >> 7, ncol = so & 127;
            short8 v = *(const short8*)&lout[so];
            *(short8*)&dst[(size_t)(mbase + mrow) * 2048 + ncb + ncol] = v;
        }
    } else {
        #pragma unroll
        for (int j = 0; j < 4; ++j) {
            const int n = nbase + nt + j * 16;
            #pragma unroll
            for (int i = 0; i < MI; ++i) {
                #pragma unroll
                for (int r = 0; r < 4; ++r)
                    atomicAdd(&outp[(size_t)(mbase + mt + i * 16 + r) * 1024 + n],
                              acc[i][j][r]);
            }
        }
    }
}

// ---------------- chunked selective scan (bf16 xp/dl), NC=64 -----------------
constexpr int NC = 64, CL = 16;

__global__ __launch_bounds__(256) void scan_phaseA(
    const unsigned short* __restrict__ xp, const unsigned short* __restrict__ dl,
    const float* __restrict__ A_log, const float* __restrict__ B_mat,
    float* __restrict__ Q, float* __restrict__ sumdt)
{
    const int ch = blockIdx.x * 256 + threadIdx.x;
    const int c = blockIdx.y;
    const int d = ch & 2047, b = ch >> 11;
    float Ac[16], Bv[16], h[16];
    #pragma unroll
    for (int s = 0; s < 16; ++s) {
        Ac[s] = -fexp2(A_log[d * 16 + s] * LOG2E) * LOG2E;
        Bv[s] = B_mat[d * 16 + s];
        h[s] = 0.0f;
    }
    float sd = 0.0f;
    size_t idx = ((size_t)b * 1024 + (size_t)c * CL) * 2048 + d;
    for (int t = 0; t < CL; ++t, idx += 2048) {
        const float xt = bf2f(xp[idx]), dt = bf2f(dl[idx]);
        sd += dt;
        const float xdt = xt * dt;
        #pragma unroll
        for (int s = 0; s < 16; ++s)
            h[s] = fmaf(h[s], fexp2(Ac[s] * dt), xdt * Bv[s]);
    }
    float* q = Q + ((size_t)ch * NC + c) * 16;
    #pragma unroll
    for (int s = 0; s < 16; ++s) q[s] = h[s];
    sumdt[ch * NC + c] = sd;
}

__global__ __launch_bounds__(256) void scan_phaseB(
    const float* __restrict__ A_log, const float* __restrict__ Q,
    const float* __restrict__ sumdt, float* __restrict__ hst)
{
    const int s = threadIdx.x & 15;
    const int ch = blockIdx.x * 16 + (threadIdx.x >> 4);
    const int d = ch & 2047;
    const float Ac = -fexp2(A_log[d * 16 + s] * LOG2E) * LOG2E;
    float h = 0.0f;
    const float* q = Q + (size_t)ch * NC * 16 + s;
    const float* sd = sumdt + ch * NC;
    float* hs = hst + (size_t)ch * NC * 16 + s;
    for (int c = 0; c < NC; ++c) {
        hs[c * 16] = h;
        h = fmaf(h, fexp2(Ac * sd[c]), q[c * 16]);
    }
}

__global__ __launch_bounds__(256) void scan_phaseC(
    const unsigned short* __restrict__ xp, const unsigned short* __restrict__ dl,
    const float* __restrict__ A_log, const float* __restrict__ B_mat,
    const float* __restrict__ C_mat, const float* __restrict__ D_vec,
    const unsigned short* __restrict__ gate, const float* __restrict__ hst,
    unsigned short* __restrict__ z)
{
    const int ch = blockIdx.x * 256 + threadIdx.x;
    const int c = blockIdx.y;
    const int d = ch & 2047, b = ch >> 11;
    float Ac[16], Bv[16], Cv[16], h[16];
    #pragma unroll
    for (int s = 0; s < 16; ++s) {
        Ac[s] = -fexp2(A_log[d * 16 + s] * LOG2E) * LOG2E;
        Bv[s] = B_mat[d * 16 + s];
        Cv[s] = C_mat[s];
        h[s] = hst[((size_t)ch * NC + c) * 16 + s];
    }
    const float Dv = D_vec[d];
    size_t idx = ((size_t)b * 1024 + (size_t)c * CL) * 2048 + d;
    for (int t = 0; t < CL; ++t, idx += 2048) {
        const float xt = bf2f(xp[idx]), dt = bf2f(dl[idx]);
        const float xdt = xt * dt;
        float y = 0.0f;
        #pragma unroll
        for (int s = 0; s < 16; ++s) {
            h[s] = fmaf(h[s], fexp2(Ac[s] * dt), xdt * Bv[s]);
            y = fmaf(h[s], Cv[s], y);
        }
        const float g = bf2f(gate[idx]);
        z[idx] = f2bf(g * (y + xt * Dv));
    }
}

// ---------------------------------------------------------------------------
extern "C" void kernel_launch(void* const* d_in, const int* in_sizes, int n_in,
                              void* d_out, int out_size, void* d_ws, size_t ws_size,
                              hipStream_t stream) {
    const float* x      = (const float*)d_in[0];
    const float* W_in   = (const float*)d_in[1];
    const float* b_in   = (const float*)d_in[2];
    const float* W_gate = (const float*)d_in[3];
    const float* b_gate = (const float*)d_in[4];
    const float* W_out  = (const float*)d_in[5];
    const float* b_out  = (const float*)d_in[6];
    const float* A_log  = (const float*)d_in[7];
    const float* B_mat  = (const float*)d_in[8];
    const float* C_mat  = (const float*)d_in[9];
    const float* D_vec  = (const float*)d_in[10];
    float* out = (float*)d_out;

    // workspace: f32 region first, bf16 after
    float* fws = (float*)d_ws;
    float* Q     = fws;                         //  4,194,304 f32 (4096*64*16)
    float* hst   = Q + 4194304;                 //  4,194,304 f32
    float* sumdt = hst + 4194304;               //    262,144 f32
    unsigned short* us = (unsigned short*)(sumdt + 262144);
    unsigned short* gate  = us;                 //  4,194,304 bf16
    unsigned short* z     = gate  + 4194304;    //  4,194,304 bf16
    unsigned short* xproj = z     + 4194304;    //  4,194,304 bf16
    unsigned short* delta = xproj + 4194304;    //  4,194,304 bf16
    unsigned short* x_bf  = delta + 4194304;    //  2,097,152 bf16
    unsigned short* wg_bf = x_bf  + 2097152;    //  2,097,152 bf16
    unsigned short* wi_bf = wg_bf + 2097152;    //  4,194,304 bf16
    unsigned short* wo_bf = wi_bf + 4194304;    //  2,097,152 bf16

    dim3 blk(256);
    // cast (5120 blocks, 8 elems/thread) + out=bias init (1024 blocks)
    cast_and_init<<<6144, blk, 0, stream>>>(x, W_gate, W_in, W_out,
                                            x_bf, wg_bf, wi_bf, wo_bf, b_out, out);
    // fused: gate = sigmoid(x@Wg^T+bg) ; proj -> xproj | relu delta (all bf16)
    gemm_mfma<3, 4><<<dim3(48, 16), blk, 0, stream>>>(
        x_bf, wg_bf, wi_bf, b_gate, b_in, gate, xproj, delta, nullptr, 1024, 1024);
    scan_phaseA<<<dim3(16, NC), blk, 0, stream>>>(xproj, delta, A_log, B_mat, Q, sumdt);
    scan_phaseB<<<256, blk, 0, stream>>>(A_log, Q, sumdt, hst);
    scan_phaseC<<<dim3(16, NC), blk, 0, stream>>>(xproj, delta, A_log, B_mat, C_mat, D_vec, gate, hst, z);
    // out += z @ W_out^T (K split in 2, atomic f32; out pre-initialized to bias)
    gemm_mfma<2, 2><<<dim3(8, 32, 2), blk, 0, stream>>>(
        z, wo_bf, nullptr, nullptr, nullptr, nullptr, nullptr, nullptr, out, 2048, 1024);
}

// Round 11
// 206.264 us; speedup vs baseline: 1.0049x; 1.0049x over previous
//
#include <hip/hip_runtime.h>
#include <hip/hip_bf16.h>

// MambaStateSpaceLayer: B=2, S=1024, D_MODEL=1024, D_STATE=16, D_INNER=2048
// Round 11 (final consolidation): r8 config (best measured, 205.4us) + 8-wide
// cast from r10. T1 swizzle REVERTED (neutral-to-negative at this L2-resident
// shape, r10 A/B). GEMM: r3 m97-structure (BM=128, MI=4, 32KB LDS, 768 blocks,
// 3/CU); bf16 everything via LDS-repack epilogue; scans NC=64 3-phase.

#define LOG2E 1.4426950408889634f

typedef float floatx4 __attribute__((ext_vector_type(4)));
typedef short short8 __attribute__((ext_vector_type(8)));

__device__ __forceinline__ float fexp2(float x) { return __builtin_amdgcn_exp2f(x); }
__device__ __forceinline__ unsigned short f2bf(float f) {
    unsigned int u = __float_as_uint(f);
    u = (u + 0x7fffu + ((u >> 16) & 1u)) >> 16;   // round-to-nearest-even
    return (unsigned short)u;
}
__device__ __forceinline__ float bf2f(unsigned short h) {
    return __uint_as_float(((unsigned int)h) << 16);
}

// async 16B global -> LDS. lp MUST be wave-uniform (HW adds lane*16).
#define GLDS16(gp, lp) __builtin_amdgcn_global_load_lds(                      \
    (const __attribute__((address_space(1))) void*)(gp),                      \
    (__attribute__((address_space(3))) void*)(lp), 16, 0, 0)

// ------- cast x, W_gate, W_in, W_out to bf16 + init out=bias (8 elems/thread)
__global__ __launch_bounds__(256) void cast_and_init(
    const float* __restrict__ x, const float* __restrict__ wg,
    const float* __restrict__ wi, const float* __restrict__ wo,
    unsigned short* __restrict__ ox, unsigned short* __restrict__ owg,
    unsigned short* __restrict__ owi, unsigned short* __restrict__ owo,
    const float* __restrict__ b_out, float* __restrict__ out)
{
    const int bid = blockIdx.x;
    if (bid < 5120) {
        const size_t e = ((size_t)bid * 256 + threadIdx.x) * 8;
        const float* src; unsigned short* dst; size_t off;
        if (e < 2097152)      { src = x;  dst = ox;  off = e; }
        else if (e < 4194304) { src = wg; dst = owg; off = e - 2097152; }
        else if (e < 8388608) { src = wi; dst = owi; off = e - 4194304; }
        else                  { src = wo; dst = owo; off = e - 8388608; }
        float4 v0 = *(const float4*)(src + off);
        float4 v1 = *(const float4*)(src + off + 4);
        short8 o;
        o[0] = (short)f2bf(v0.x); o[1] = (short)f2bf(v0.y);
        o[2] = (short)f2bf(v0.z); o[3] = (short)f2bf(v0.w);
        o[4] = (short)f2bf(v1.x); o[5] = (short)f2bf(v1.y);
        o[6] = (short)f2bf(v1.z); o[7] = (short)f2bf(v1.w);
        *(short8*)(dst + off) = o;
    } else {
        const size_t e = ((size_t)(bid - 5120) * 256 + threadIdx.x) * 8;
        const int col = (int)(e & 1023);
        *(float4*)(out + e)     = *(const float4*)(b_out + col);
        *(float4*)(out + e + 4) = *(const float4*)(b_out + col + 4);
    }
}

// ---------------- MFMA GEMM (r3 structure, r7 epilogue) ----------------------
// C = A[M,ldk] @ W[N,ldk]^T (+ bias).  BK=64 bf16 (128B rows, 8x16B slots).
// Staging: global_load_lds dwordx4, linear LDS dest; source slot pre-swizzled
// (l&7)^(l>>3); ds_read uses slot ^ (row&7)  [both-sides-or-neither].
// Block = 4 waves (2x2). Wave tile = (MI*16) x 64. BM = MI*32, BN = 128.
// MODE 3 (MI=4): fused input GEMM. blockIdx.x<16 -> gate=sigmoid; else proj:
//   n<2048 -> xproj, n>=2048 -> relu -> delta.  ALL outputs bf16, written via
//   LDS repack (tile -> 32KB LDS as bf16 -> coalesced 16B/lane linear stores).
// MODE 2 (MI=2): K-split over blockIdx.z (Ksub each); atomicAdd f32 into outp.
template <int MODE, int MI>
__global__ __launch_bounds__(256, 3) void gemm_mfma(
    const unsigned short* __restrict__ A,
    const unsigned short* __restrict__ W0,
    const unsigned short* __restrict__ W1,
    const float* __restrict__ bias0, const float* __restrict__ bias1,
    unsigned short* __restrict__ gate,
    unsigned short* __restrict__ xproj, unsigned short* __restrict__ delta,
    float* __restrict__ outp, int ldk, int Ksub)
{
    constexpr int BM = MI * 32;
    constexpr int ROWA = BM / 32;          // A 1KB staging blocks per wave
    constexpr int NSH = (MODE == 3) ? 16384 : (BM * 64 + 8192);
    __shared__ short smem[NSH];            // staging; MODE 3 reuses as repack buf
    short* Asd = smem;                     // BM*64 shorts
    short* Bsd = smem + BM * 64;           // 128*64 shorts

    const int tid = threadIdx.x;
    const int l = tid & 63, w = tid >> 6;
    const int mbase = blockIdx.y * BM;
    const int kbeg = (MODE == 2) ? blockIdx.z * Ksub : 0;
    const int kend = kbeg + Ksub;

    const unsigned short* Wp; const float* bias = nullptr; int nbase; bool isGate = false;
    if (MODE == 3) {
        const int bx = blockIdx.x;
        if (bx < 16) { Wp = W0; bias = bias0; nbase = bx * 128; isGate = true; }
        else         { Wp = W1; bias = bias1; nbase = (bx - 16) * 128; }
    } else { Wp = W0; nbase = blockIdx.x * 128; }

    // per-lane staging source offsets (elements, k0 added per iter)
    const int rl = l >> 3;                 // row within 8-row block
    const int cs = (l & 7) ^ rl;           // inverse-swizzled source slot
    size_t aoff[ROWA], boff[4];
    #pragma unroll
    for (int j = 0; j < ROWA; ++j)
        aoff[j] = (size_t)(mbase + (w * ROWA + j) * 8 + rl) * ldk + cs * 8;
    #pragma unroll
    for (int j = 0; j < 4; ++j)
        boff[j] = (size_t)(nbase + (w * 4 + j) * 8 + rl) * ldk + cs * 8;

    const int wm = (w >> 1) * (MI * 16), wn = (w & 1) * 64;
    floatx4 acc[MI][4] = {};

    for (int k0 = kbeg; k0 < kend; k0 += 64) {
        __syncthreads();                   // prior tile's ds_reads complete
        #pragma unroll
        for (int j = 0; j < ROWA; ++j)
            GLDS16(A + aoff[j] + k0, &Asd[(w * ROWA + j) * 512]);
        #pragma unroll
        for (int j = 0; j < 4; ++j)
            GLDS16(Wp + boff[j] + k0, &Bsd[(w * 4 + j) * 512]);
        __syncthreads();                   // vmcnt(0) drained by compiler

        #pragma unroll
        for (int kk = 0; kk < 2; ++kk) {
            short8 af[MI], bfr[4];
            #pragma unroll
            for (int i = 0; i < MI; ++i) {
                const int row = wm + i * 16 + (l & 15);
                af[i] = *(const short8*)&Asd[row * 64 + (((kk * 4 + (l >> 4)) ^ (row & 7)) << 3)];
            }
            #pragma unroll
            for (int j = 0; j < 4; ++j) {
                const int row = wn + j * 16 + (l & 15);
                bfr[j] = *(const short8*)&Bsd[row * 64 + (((kk * 4 + (l >> 4)) ^ (row & 7)) << 3)];
            }
            #pragma unroll
            for (int i = 0; i < MI; ++i)
                #pragma unroll
                for (int j = 0; j < 4; ++j)
                    acc[i][j] = __builtin_amdgcn_mfma_f32_16x16x32_bf16(af[i], bfr[j], acc[i][j], 0, 0, 0);
        }
    }

    // epilogue: D col = lane&15, row = (lane>>4)*4 + reg  [m89-verified]
    const int mt = wm + (l >> 4) * 4;      // tile-local row base
    const int nt = wn + (l & 15);          // tile-local col base
    if (MODE == 3) {
        // 1) bf16 tile -> LDS [128][128]
        __syncthreads();                   // staging reads done; reuse smem
        unsigned short* lout = (unsigned short*)smem;
        #pragma unroll
        for (int j = 0; j < 4; ++j) {
            const float bb = bias[nbase + nt + j * 16];
            #pragma unroll
            for (int i = 0; i < MI; ++i) {
                #pragma unroll
                for (int r = 0; r < 4; ++r) {
                    float v = acc[i][j][r] + bb;
                    if (isGate) v = 1.0f / (1.0f + fexp2(-v * LOG2E));
                    else if (nbase >= 2048) v = fmaxf(v, 0.0f);
                    lout[(mt + i * 16 + r) * 128 + nt + j * 16] = f2bf(v);
                }
            }
        }
        __syncthreads();
        // 2) coalesced linear copy LDS -> global (full 64B+ lines)
        unsigned short* dst = isGate ? gate : (nbase < 2048 ? xproj : delta);
        const int ncb = nbase & 2047;      // col base within 2048-wide buffer
        #pragma unroll
        for (int it = 0; it < 8; ++it) {
            const int so = it * 2048 + tid * 8;       // short offset in tile
            const int mrow = so >> 7, ncol = so & 127;
            short8 v = *(const short8*)&lout[so];
            *(short8*)&dst[(size_t)(mbase + mrow) * 2048 + ncb + ncol] = v;
        }
    } else {
        #pragma unroll
        for (int j = 0; j < 4; ++j) {
            const int n = nbase + nt + j * 16;
            #pragma unroll
            for (int i = 0; i < MI; ++i) {
                #pragma unroll
                for (int r = 0; r < 4; ++r)
                    atomicAdd(&outp[(size_t)(mbase + mt + i * 16 + r) * 1024 + n],
                              acc[i][j][r]);
            }
        }
    }
}

// ---------------- chunked selective scan (bf16 xp/dl), NC=64 -----------------
constexpr int NC = 64, CL = 16;

__global__ __launch_bounds__(256) void scan_phaseA(
    const unsigned short* __restrict__ xp, const unsigned short* __restrict__ dl,
    const float* __restrict__ A_log, const float* __restrict__ B_mat,
    float* __restrict__ Q, float* __restrict__ sumdt)
{
    const int ch = blockIdx.x * 256 + threadIdx.x;
    const int c = blockIdx.y;
    const int d = ch & 2047, b = ch >> 11;
    float Ac[16], Bv[16], h[16];
    #pragma unroll
    for (int s = 0; s < 16; ++s) {
        Ac[s] = -fexp2(A_log[d * 16 + s] * LOG2E) * LOG2E;
        Bv[s] = B_mat[d * 16 + s];
        h[s] = 0.0f;
    }
    float sd = 0.0f;
    size_t idx = ((size_t)b * 1024 + (size_t)c * CL) * 2048 + d;
    for (int t = 0; t < CL; ++t, idx += 2048) {
        const float xt = bf2f(xp[idx]), dt = bf2f(dl[idx]);
        sd += dt;
        const float xdt = xt * dt;
        #pragma unroll
        for (int s = 0; s < 16; ++s)
            h[s] = fmaf(h[s], fexp2(Ac[s] * dt), xdt * Bv[s]);
    }
    float* q = Q + ((size_t)ch * NC + c) * 16;
    #pragma unroll
    for (int s = 0; s < 16; ++s) q[s] = h[s];
    sumdt[ch * NC + c] = sd;
}

__global__ __launch_bounds__(256) void scan_phaseB(
    const float* __restrict__ A_log, const float* __restrict__ Q,
    const float* __restrict__ sumdt, float* __restrict__ hst)
{
    const int s = threadIdx.x & 15;
    const int ch = blockIdx.x * 16 + (threadIdx.x >> 4);
    const int d = ch & 2047;
    const float Ac = -fexp2(A_log[d * 16 + s] * LOG2E) * LOG2E;
    float h = 0.0f;
    const float* q = Q + (size_t)ch * NC * 16 + s;
    const float* sd = sumdt + ch * NC;
    float* hs = hst + (size_t)ch * NC * 16 + s;
    for (int c = 0; c < NC; ++c) {
        hs[c * 16] = h;
        h = fmaf(h, fexp2(Ac * sd[c]), q[c * 16]);
    }
}

__global__ __launch_bounds__(256) void scan_phaseC(
    const unsigned short* __restrict__ xp, const unsigned short* __restrict__ dl,
    const float* __restrict__ A_log, const float* __restrict__ B_mat,
    const float* __restrict__ C_mat, const float* __restrict__ D_vec,
    const unsigned short* __restrict__ gate, const float* __restrict__ hst,
    unsigned short* __restrict__ z)
{
    const int ch = blockIdx.x * 256 + threadIdx.x;
    const int c = blockIdx.y;
    const int d = ch & 2047, b = ch >> 11;
    float Ac[16], Bv[16], Cv[16], h[16];
    #pragma unroll
    for (int s = 0; s < 16; ++s) {
        Ac[s] = -fexp2(A_log[d * 16 + s] * LOG2E) * LOG2E;
        Bv[s] = B_mat[d * 16 + s];
        Cv[s] = C_mat[s];
        h[s] = hst[((size_t)ch * NC + c) * 16 + s];
    }
    const float Dv = D_vec[d];
    size_t idx = ((size_t)b * 1024 + (size_t)c * CL) * 2048 + d;
    for (int t = 0; t < CL; ++t, idx += 2048) {
        const float xt = bf2f(xp[idx]), dt = bf2f(dl[idx]);
        const float xdt = xt * dt;
        float y = 0.0f;
        #pragma unroll
        for (int s = 0; s < 16; ++s) {
            h[s] = fmaf(h[s], fexp2(Ac[s] * dt), xdt * Bv[s]);
            y = fmaf(h[s], Cv[s], y);
        }
        const float g = bf2f(gate[idx]);
        z[idx] = f2bf(g * (y + xt * Dv));
    }
}

// ---------------------------------------------------------------------------
extern "C" void kernel_launch(void* const* d_in, const int* in_sizes, int n_in,
                              void* d_out, int out_size, void* d_ws, size_t ws_size,
                              hipStream_t stream) {
    const float* x      = (const float*)d_in[0];
    const float* W_in   = (const float*)d_in[1];
    const float* b_in   = (const float*)d_in[2];
    const float* W_gate = (const float*)d_in[3];
    const float* b_gate = (const float*)d_in[4];
    const float* W_out  = (const float*)d_in[5];
    const float* b_out  = (const float*)d_in[6];
    const float* A_log  = (const float*)d_in[7];
    const float* B_mat  = (const float*)d_in[8];
    const float* C_mat  = (const float*)d_in[9];
    const float* D_vec  = (const float*)d_in[10];
    float* out = (float*)d_out;

    // workspace: f32 region first, bf16 after
    float* fws = (float*)d_ws;
    float* Q     = fws;                         //  4,194,304 f32 (4096*64*16)
    float* hst   = Q + 4194304;                 //  4,194,304 f32
    float* sumdt = hst + 4194304;               //    262,144 f32
    unsigned short* us = (unsigned short*)(sumdt + 262144);
    unsigned short* gate  = us;                 //  4,194,304 bf16
    unsigned short* z     = gate  + 4194304;    //  4,194,304 bf16
    unsigned short* xproj = z     + 4194304;    //  4,194,304 bf16
    unsigned short* delta = xproj + 4194304;    //  4,194,304 bf16
    unsigned short* x_bf  = delta + 4194304;    //  2,097,152 bf16
    unsigned short* wg_bf = x_bf  + 2097152;    //  2,097,152 bf16
    unsigned short* wi_bf = wg_bf + 2097152;    //  4,194,304 bf16
    unsigned short* wo_bf = wi_bf + 4194304;    //  2,097,152 bf16

    dim3 blk(256);
    // cast (5120 blocks, 8 elems/thread) + out=bias init (1024 blocks)
    cast_and_init<<<6144, blk, 0, stream>>>(x, W_gate, W_in, W_out,
                                            x_bf, wg_bf, wi_bf, wo_bf, b_out, out);
    // fused: gate = sigmoid(x@Wg^T+bg) ; proj -> xproj | relu delta (all bf16)
    gemm_mfma<3, 4><<<dim3(48, 16), blk, 0, stream>>>(
        x_bf, wg_bf, wi_bf, b_gate, b_in, gate, xproj, delta, nullptr, 1024, 1024);
    scan_phaseA<<<dim3(16, NC), blk, 0, stream>>>(xproj, delta, A_log, B_mat, Q, sumdt);
    scan_phaseB<<<256, blk, 0, stream>>>(A_log, Q, sumdt, hst);
    scan_phaseC<<<dim3(16, NC), blk, 0, stream>>>(xproj, delta, A_log, B_mat, C_mat, D_vec, gate, hst, z);
    // out += z @ W_out^T (K split in 2, atomic f32; out pre-initialized to bias)
    gemm_mfma<2, 2><<<dim3(8, 32, 2), blk, 0, stream>>>(
        z, wo_bf, nullptr, nullptr, nullptr, nullptr, nullptr, nullptr, out, 2048, 1024);
}